// Round 11
// baseline (99.977 us; speedup 1.0000x reference)
//
#include <hip/hip_runtime.h>

// LIF neuron forward, v6: 256 blocks x 32 channels — engage every CU.
// V = leak*V + I; spike = (V >= 1); V -= spike.
// current: [B=8, S=4096, D=1024] f32, membrane: [B, D] f32.
// Outputs concatenated: spikes [B,S,D] then mem_final [B,D], all f32.
//
// v5 post-mortem (94.3us): per-CU traffic 32KB/phase over 3540cy = 9.1 B/cy
// ~= the per-CU vector-memory pipe rate (10.2 B/cy from the 6.3TB/s copy
// ubench) -> 128-block grids idle half the chip's memory pipes. v6 halves
// per-block traffic (32 ch/block, 256 blocks) so all 256 CUs stream.
// Same 3-stage skeleton as v5: w0 consumer (lanes 0-31), w1 producer
// (8x1KB global_load_lds, 3 chunks ahead, vmcnt(16) counted wait),
// w2-3 writers (ds_read_b128 + global_store_dwordx4).
//
// Numerics (validated r5-r10, absmax 7.6e-6): forward spike == hard
// threshold exactly in fp32; fp contract(off) pins mul-then-add rounding.

#define LIF_B 8
#define LIF_S 4096
#define LIF_D 1024
#define CHUNK 64
#define NH    (LIF_S / CHUNK)   // 64
#define CPB   32                // channels per block

typedef __attribute__((address_space(3))) unsigned int lds_uint;
typedef const __attribute__((address_space(1))) unsigned int glb_uint;

// stage one 8KB chunk (64 rows x 32 ch) with 8 x 1KB global_load_lds.
// lane L -> row (L>>3) within an 8-row group, float col (L&7)*4.
// LDS dest linear (m173 pattern): slotbase + f*256 floats.
__device__ __forceinline__ void stage_chunk32(const float* gwin, int tb,
                                              int prow, int pcol,
                                              float* slotbase) {
    #pragma unroll
    for (int f = 0; f < 8; ++f) {
        const float* src = gwin + (size_t)(tb + 8 * f + prow) * LIF_D + pcol;
        __builtin_amdgcn_global_load_lds(
            (glb_uint*)(const void*)src,
            (lds_uint*)(void*)(slotbase + (size_t)f * 256), 16, 0, 0);
    }
}

__global__ __launch_bounds__(256, 1) void lif_v6_kernel(
    const float* __restrict__ current,
    const float* __restrict__ membrane,
    float* __restrict__ spikes,
    float* __restrict__ mem_out)
{
    #pragma clang fp contract(off)

    __shared__ __align__(16) float in_ring [4][CHUNK][CPB];   // 32 KB
    __shared__ __align__(16) float out_ring[2][CHUNK][CPB];   // 16 KB

    const int wid  = threadIdx.x >> 6;   // 0=consumer 1=producer 2,3=writers
    const int lane = threadIdx.x & 63;
    const int blk  = blockIdx.x;         // 0..255
    const int bb   = blk >> 5;           // batch (1024/32 = 32 ch-blocks)
    const int ch0  = (blk & 31) * CPB;

    const float* gwin  = current + (size_t)bb * LIF_S * LIF_D + ch0;
    float*       sbase = spikes  + (size_t)bb * LIF_S * LIF_D + ch0;

    const int prow = lane >> 3;          // 0..7 : row within 8-row group
    const int pcol = (lane & 7) * 4;     // float col (16B units)

    float mem = 0.0f;

    // ---- prologue: producer stages chunks 0..2; consumer loads membrane ----
    if (wid == 1) {
        stage_chunk32(gwin, 0 * CHUNK, prow, pcol, &in_ring[0][0][0]);
        stage_chunk32(gwin, 1 * CHUNK, prow, pcol, &in_ring[1][0][0]);
        stage_chunk32(gwin, 2 * CHUNK, prow, pcol, &in_ring[2][0][0]);
        asm volatile("s_waitcnt vmcnt(16)" ::: "memory");  // chunk 0 landed
    } else if (wid == 0 && lane < CPB) {
        mem = membrane[bb * LIF_D + ch0 + lane];
    }
    __builtin_amdgcn_s_barrier();
    asm volatile("" ::: "memory");

    for (int h = 0; h < NH; ++h) {
        if (wid == 0) {
            if (lane < CPB) {
                // ---- consumer: chunk h, all-immediate LDS addressing ----
                const float* ib = &in_ring [h & 3][0][lane];
                float*       ob = &out_ring[h & 1][0][lane];

                float pre[8], nxt[8];
                #pragma unroll
                for (int j = 0; j < 8; ++j) pre[j] = ib[j * CPB];

                for (int r0 = 0; r0 < CHUNK; r0 += 8) {
                    if (r0 + 8 < CHUNK) {
                        #pragma unroll
                        for (int j = 0; j < 8; ++j) nxt[j] = ib[(r0 + 8 + j) * CPB];
                    }
                    #pragma unroll
                    for (int j = 0; j < 8; ++j) {
                        const float v = 0.9f * mem + pre[j];   // mul-then-add
                        const float w = v - 1.0f;              // off chain
                        const bool  f = (v >= 1.0f);
                        ob[(r0 + j) * CPB] = f ? 1.0f : 0.0f;
                        mem = f ? w : v;                       // soft reset
                    }
                    #pragma unroll
                    for (int j = 0; j < 8; ++j) pre[j] = nxt[j];
                }
            }
            asm volatile("s_waitcnt lgkmcnt(0)" ::: "memory");
        } else if (wid == 1) {
            // ---- producer: stage chunk h+3; 16 loads stay in flight ----
            if (h + 3 < NH) {
                stage_chunk32(gwin, (h + 3) * CHUNK, prow, pcol,
                              &in_ring[(h + 3) & 3][0][0]);
                asm volatile("s_waitcnt vmcnt(16)" ::: "memory");
            } else {
                asm volatile("s_waitcnt vmcnt(0)" ::: "memory");
            }
        } else {
            // ---- writers: flush out[h-1] (4 x 1KB each) ----
            if (h >= 1) {
                const int tbase = (h - 1) * CHUNK;
                const float4* o4 = (const float4*)&out_ring[(h - 1) & 1][0][0];
                #pragma unroll
                for (int k = 0; k < 4; ++k) {
                    const int f = (wid - 2) + 2 * k;      // 8 groups over 2 waves
                    const float4 vv = o4[f * 64 + lane];  // 8 rows x 8 f4
                    const int    t  = tbase + 8 * f + prow;
                    *(float4*)(sbase + (size_t)t * LIF_D + pcol) = vv;
                }
                asm volatile("s_waitcnt lgkmcnt(0)" ::: "memory");
            }
        }
        __builtin_amdgcn_s_barrier();
        asm volatile("" ::: "memory");
    }

    // ---- epilogue: flush out[NH-1]; store final membrane ----
    if (wid >= 2) {
        const int tbase = (NH - 1) * CHUNK;
        const float4* o4 = (const float4*)&out_ring[(NH - 1) & 1][0][0];
        #pragma unroll
        for (int k = 0; k < 4; ++k) {
            const int f = (wid - 2) + 2 * k;
            const float4 vv = o4[f * 64 + lane];
            const int    t  = tbase + 8 * f + prow;
            *(float4*)(sbase + (size_t)t * LIF_D + pcol) = vv;
        }
    } else if (wid == 0 && lane < CPB) {
        mem_out[bb * LIF_D + ch0 + lane] = mem;
    }
}

extern "C" void kernel_launch(void* const* d_in, const int* in_sizes, int n_in,
                              void* d_out, int out_size, void* d_ws, size_t ws_size,
                              hipStream_t stream) {
    const float* current  = (const float*)d_in[0];   // [8, 4096, 1024]
    const float* membrane = (const float*)d_in[1];   // [8, 1024]

    float* spikes  = (float*)d_out;                                 // [8,4096,1024]
    float* mem_out = (float*)d_out + (size_t)LIF_B * LIF_S * LIF_D; // [8,1024]

    dim3 block(256);                    // w0 consumer, w1 producer, w2-3 writers
    dim3 grid(LIF_B * LIF_D / CPB);     // 256 blocks (32 channels each)

    hipLaunchKernelGGL(lif_v6_kernel, grid, block, 0, stream,
                       current, membrane, spikes, mem_out);
}